// Round 14
// baseline (227.052 us; speedup 1.0000x reference)
//
#include <hip/hip_runtime.h>

#define B_   32
#define L_   512
#define D_   384
#define M_   (B_*L_)    // 16384 rows
#define KTOT (D_*3)     // 1152 GEMM K
#define LDW  392        // LDS row stride in bf16 elems (784B: 16B-aligned, 2-way bank alias)
#define BROWS 82        // 80 data rows + 2 guard rows
#define BUFE (BROWS*LDW)
#define RPBLK 1728      // repack blocks per weight (1728*256 == D_*KTOT exactly)
#define RPTOT (4*RPBLK) // 6912
#define SCAT  8192      // scatter blocks (2 phonemes each)
#define ZT    (16*B_)   // 512 ztail blocks

typedef __bf16 bf16x8 __attribute__((ext_vector_type(8)));
typedef float  floatx4 __attribute__((ext_vector_type(4)));

// ================= K_A: repack + scatter(self-cum) + ztail, ONE launch ============
// r18-proven. Blocks [0, RPTOT): weight repack. Blocks [RPTOT, RPTOT+SCAT):
// scatter, 2 phonemes/block, self-computed cum (wave-0 scan into LDS).
// Blocks [RPTOT+SCAT, +ZT): tail zero-fill, 16 blocks/batch.
// ~180 MB of traffic -> ~28 us floor; measured ~30 us. Near its roofline.
__global__ __launch_bounds__(256) void mega_prep_lr(const float* __restrict__ wa,
                                                    const float* __restrict__ wb,
                                                    const float* __restrict__ wc,
                                                    const float* __restrict__ wd,
                                                    __bf16* __restrict__ oa,
                                                    __bf16* __restrict__ ob,
                                                    __bf16* __restrict__ oc,
                                                    __bf16* __restrict__ od,
                                                    const int* __restrict__ dur,
                                                    const float* __restrict__ x,
                                                    float* __restrict__ out, int T)
{
    __shared__ int scum[512];
    int bx = blockIdx.x;

    if (bx < RPTOT) {
        // ---- weight repack: W3[((c*24+t)*64+lane)*8+j] = w[o][kflat] ----
        int wi  = bx / RPBLK;
        int idx = (bx - wi * RPBLK) * 256 + threadIdx.x;
        const float* w; __bf16* o_;
        switch (wi) {
            case 0:  w = wa; o_ = oa; break;
            case 1:  w = wb; o_ = ob; break;
            case 2:  w = wc; o_ = oc; break;
            default: w = wd; o_ = od; break;
        }
        int j  = idx & 7;
        int l  = (idx >> 3) & 63;
        int ct = idx >> 9;          // c*24 + t
        int c  = ct / 24;
        int t  = ct - c * 24;
        int o  = t * 16 + (l & 15);
        int kflat = c * 32 + (l >> 4) * 8 + j;
        int s  = kflat / D_;
        int i  = kflat - s * D_;
        o_[idx] = (__bf16)w[(o * D_ + i) * 3 + s];
        return;
    }

    if (bx < RPTOT + SCAT) {
        // ---- scatter: block handles phonemes pl0, pl0+1 (same batch) ----
        int sx  = bx - RPTOT;
        int pl0 = sx * 2;
        int b   = pl0 >> 9;
        const int* db = dur + b * L_;
        if (threadIdx.x < 64) {
            int lane = threadIdx.x;
            int v[8], s = 0;
#pragma unroll
            for (int i = 0; i < 8; i++) { v[i] = db[lane * 8 + i]; s += v[i]; }
            int ex = s;
#pragma unroll
            for (int off = 1; off < 64; off <<= 1) {
                int n = __shfl_up(ex, off);
                if (lane >= off) ex += n;
            }
            ex -= s;
            int c = ex;
#pragma unroll
            for (int i = 0; i < 8; i++) { c += v[i]; scum[lane * 8 + i] = c; }
        }
        __syncthreads();
        int sub = threadIdx.x >> 7;               // 0 or 1
        int q   = threadIdx.x & 127;
        int l   = (pl0 & 511) + sub;
        int e = scum[l];
        int s = l ? scum[l - 1] : 0;
        if (e == s || q >= 96) return;
        int pl = b * L_ + l;
        float4 v = *(const float4*)(x + (size_t)pl * D_ + q * 4);
        float* ob_ = out + ((size_t)b * T) * D_ + q * 4;
        for (int t = s; t < e; ++t)
            *(float4*)(ob_ + (size_t)t * D_) = v;
        return;
    }

    // ---- tail zero-fill [total_b, T): 16 blocks per batch ----
    int zb = bx - RPTOT - SCAT;
    int bxi = zb & 15;
    int b   = zb >> 4;
    if (threadIdx.x < 64) {
        int lane = threadIdx.x;
        int s = 0;
#pragma unroll
        for (int i = 0; i < 8; i++) s += dur[b * L_ + lane * 8 + i];
#pragma unroll
        for (int off = 1; off < 64; off <<= 1) s += __shfl_xor(s, off);
        if (lane == 0) scum[0] = s;
    }
    __syncthreads();
    int total = scum[0];
    int nfr = T - total;
    if (nfr <= 0) return;
    float* base = out + ((size_t)b * T + total) * D_;
    int n4 = nfr * 96;                // float4 stores
    for (int i = bxi * 256 + threadIdx.x; i < n4; i += 4096) {
        int fr = i / 96, q = i - fr * 96;
        *(float4*)(base + (size_t)fr * D_ + q * 4) = make_float4(0.f, 0.f, 0.f, 0.f);
    }
}

// ================= K_B: fused DurationPredictor (r21: waves_per_eu(2,2)) ==========
// 512 threads (8 waves) own 64 output rows. 2M x 4N wave decomposition:
// ng = wave&3 owns cols [ng*96, ng*96+96) (6 n-tiles); mg = wave>>2 owns
// m-tiles {0,1,2} or {3,4}. af double-buffered (r20), bg 2-ahead.
// r21 delta: amdgpu_waves_per_eu(2,2) replaces __launch_bounds__(512,1).
// Evidence (r20): VGPR_Count stayed 116 despite ~170 regs of declared pipeline
// state -> the allocator targets 4 waves/EU (<=128 regs), an occupancy this
// kernel can NEVER reach (134 KB dynamic LDS caps it at 1 block/CU = 2
// waves/EU; the compiler can't see dynamic LDS size). Pinning the occupancy
// target to exactly 2 waves/EU gives the scheduler a 256-reg budget so the
// declared prefetch pipeline stays live across the MFMA clusters instead of
// being compressed to just-in-time loads.
__global__ void
__attribute__((amdgpu_flat_work_group_size(512, 512), amdgpu_waves_per_eu(2, 2)))
fused_predictor(
    const float* __restrict__ x,
    const __bf16* __restrict__ w1a, const float* __restrict__ b1a,
    const __bf16* __restrict__ w1b, const float* __restrict__ b1b,
    const float* __restrict__ g1,  const float* __restrict__ e1,
    const __bf16* __restrict__ w2a, const float* __restrict__ b2a,
    const __bf16* __restrict__ w2b, const float* __restrict__ b2b,
    const float* __restrict__ g2,  const float* __restrict__ e2,
    const float* __restrict__ lw,  const float* __restrict__ lb,
    float* __restrict__ out_dur)
{
    extern __shared__ char smem_raw[];
    __bf16* bufA = (__bf16*)smem_raw;
    __bf16* bufB = bufA + BUFE;
    float*  red1 = (float*)(bufB + BUFE);    // [BROWS][8]
    float*  red2 = red1 + BROWS * 8;         // [BROWS][8]
    float*  minv = red2 + BROWS * 8;         // [BROWS][2]

    const int m0 = blockIdx.x * 64;
    const int l0 = m0 & 511;
    const int b0 = m0 - l0;

    const int tid  = threadIdx.x;
    const int wave = tid >> 6;        // 0..7
    const int lane = tid & 63;
    const int quad = lane >> 4;
    const int lx   = lane & 15;
    const int ng   = wave & 3;        // N-group: cols [ng*96, ng*96+96)
    const int mg   = wave >> 2;       // M-group: 0 -> m-tiles 0..2, 1 -> 3..4
    const int mtc  = mg ? 2 : 3;      // tiles this wave computes
    const int mtb  = mg ? 3 : 0;      // first tile index

    bf16x8 kz;
#pragma unroll
    for (int z = 0; z < 8; z++) kz[z] = (__bf16)0.f;

    // ---- stage x -> bufA (fp32->bf16, zero outside seq); zero bufB guards ----
    for (int c = tid; c < BROWS * 48; c += 512) {
        int beta = c / 48, q = c - beta * 48;
        int l = l0 + beta - 9;
        bf16x8 v = kz;
        if ((unsigned)l < (unsigned)L_) {
            const float* xr = x + (size_t)(b0 + l) * D_ + q * 8;
            const float4 f0 = *(const float4*)xr;
            const float4 f1 = *(const float4*)(xr + 4);
            v[0] = (__bf16)f0.x; v[1] = (__bf16)f0.y; v[2] = (__bf16)f0.z; v[3] = (__bf16)f0.w;
            v[4] = (__bf16)f1.x; v[5] = (__bf16)f1.y; v[6] = (__bf16)f1.z; v[7] = (__bf16)f1.w;
        }
        *(bf16x8*)(&bufA[beta * LDW + q * 8]) = v;
    }
    for (int c = tid; c < 2 * 48; c += 512) {
        int beta = (c < 48) ? 0 : 81, q = c % 48;
        *(bf16x8*)(&bufB[beta * LDW + q * 8]) = kz;
    }
    __syncthreads();

    const int t0   = ng * 6;                  // first n-tile of this wave
    const int col0 = ng * 96 + lx;            // col for ni: col0 + ni*16

    floatx4 acc[3][6];
    bf16x8  bg[3][6];

    for (int st = 0; st < 4; st++) {
        const __bf16* bin  = (st & 1) ? bufB : bufA;
        __bf16*       bout = (st & 1) ? bufA : bufB;
        const __bf16* Wp = (st == 0) ? w1a : (st == 1) ? w1b : (st == 2) ? w2a : w2b;
        const float*  bp = (st == 0) ? b1a : (st == 1) ? b1b : (st == 2) ? b2a : b2b;

#pragma unroll
        for (int mt = 0; mt < 3; mt++)
            if (mt < mtc)
#pragma unroll
                for (int ni = 0; ni < 6; ni++)
#pragma unroll
                    for (int r = 0; r < 4; r++) acc[mt][ni][r] = 0.f;

        const char* pb0 = (const char*)Wp + ((size_t)t0 * 64 + lane) * 16;
        auto loadB = [&](int buf, int n) {
            int it = n / 3, s = n - it * 3;
            const char* p = pb0 + (size_t)(s * 12 + it) * 24576;
#pragma unroll
            for (int ni = 0; ni < 6; ni++)
                bg[buf][ni] = *(const bf16x8*)(p + ni * 1024);
        };
        loadB(0, 0); loadB(1, 1);

        const __bf16* ab = bin + (mtb * 16 + lx) * LDW + quad * 8;
        bf16x8 af[2][3];
        auto loadA = [&](int bi, int n) {
            int it = n / 3, s = n - it * 3;
            af[bi][0] = *(const bf16x8*)(ab + (s) * LDW + it * 32);
            af[bi][1] = *(const bf16x8*)(ab + (16 + s) * LDW + it * 32);
            if (mtc == 3)
                af[bi][2] = *(const bf16x8*)(ab + (32 + s) * LDW + it * 32);
        };
        loadA(0, 0);
#pragma unroll
        for (int n = 0; n < 36; n++) {
            if (n + 2 < 36) loadB((n + 2) % 3, n + 2);
            if (n + 1 < 36) loadA((n + 1) & 1, n + 1);
            const int ai = n & 1;
            __builtin_amdgcn_s_setprio(1);
#pragma unroll
            for (int ni = 0; ni < 6; ni++) {
                acc[0][ni] = __builtin_amdgcn_mfma_f32_16x16x32_bf16(af[ai][0], bg[n % 3][ni], acc[0][ni], 0, 0, 0);
                acc[1][ni] = __builtin_amdgcn_mfma_f32_16x16x32_bf16(af[ai][1], bg[n % 3][ni], acc[1][ni], 0, 0, 0);
            }
            if (mtc == 3) {
#pragma unroll
                for (int ni = 0; ni < 6; ni++)
                    acc[2][ni] = __builtin_amdgcn_mfma_f32_16x16x32_bf16(af[ai][2], bg[n % 3][ni], acc[2][ni], 0, 0, 0);
            }
            __builtin_amdgcn_s_setprio(0);
        }

        // ---- epilogue: bias + relu (in regs) ----
        float bv[6];
#pragma unroll
        for (int ni = 0; ni < 6; ni++) bv[ni] = bp[col0 + ni * 16];
#pragma unroll
        for (int mt = 0; mt < 3; mt++)
            if (mt < mtc)
#pragma unroll
                for (int ni = 0; ni < 6; ni++)
#pragma unroll
                    for (int r = 0; r < 4; r++) {
                        float vv = acc[mt][ni][r] + bv[ni];
                        acc[mt][ni][r] = vv > 0.f ? vv : 0.f;
                    }

        if (st == 1 || st == 3) {
            // ---- LayerNorm: row stats via lx-shuffle + cross-wave LDS reduce ----
#pragma unroll
            for (int mt = 0; mt < 3; mt++)
                if (mt < mtc)
#pragma unroll
                    for (int r = 0; r < 4; r++) {
                        float s1 = 0.f, s2 = 0.f;
#pragma unroll
                        for (int ni = 0; ni < 6; ni++) {
                            s1 += acc[mt][ni][r];
                            s2 += acc[mt][ni][r] * acc[mt][ni][r];
                        }
#pragma unroll
                        for (int d = 1; d < 16; d <<= 1) {
                            s1 += __shfl_xor(s1, d);
                            s2 += __shfl_xor(s2, d);
                        }
                        if (lx == 0) {
                            int beta = (mtb + mt) * 16 + quad * 4 + r + 1;
                            red1[beta * 8 + wave] = s1;
                            red2[beta * 8 + wave] = s2;
                        }
                    }
            __syncthreads();
            if (tid < BROWS) {
                // owner waves of row tid: tiles 0..2 -> w in {0..3}; tiles 3..4 -> {4..7}
                int tile = (tid - 1) >> 4;
                int base = (tile >= 3) ? 4 : 0;
                float s1 = 0.f, s2 = 0.f;
#pragma unroll
                for (int k = 0; k < 4; k++) { s1 += red1[tid * 8 + base + k]; s2 += red2[tid * 8 + base + k]; }
                float mean = s1 * (1.f / D_);
                float var  = s2 * (1.f / D_) - mean * mean;
                minv[tid * 2]     = mean;
                minv[tid * 2 + 1] = rsqrtf(var + 1e-5f);
            }
            __syncthreads();
            const float* gp = (st == 1) ? g1 : g2;
            const float* ep = (st == 1) ? e1 : e2;
            float gv[6], ev[6];
#pragma unroll
            for (int ni = 0; ni < 6; ni++) { gv[ni] = gp[col0 + ni * 16]; ev[ni] = ep[col0 + ni * 16]; }
#pragma unroll
            for (int mt = 0; mt < 3; mt++)
                if (mt < mtc)
#pragma unroll
                    for (int r = 0; r < 4; r++) {
                        int beta = (mtb + mt) * 16 + quad * 4 + r + 1;
                        float mean = minv[beta * 2], inv = minv[beta * 2 + 1];
#pragma unroll
                        for (int ni = 0; ni < 6; ni++)
                            acc[mt][ni][r] = (acc[mt][ni][r] - mean) * inv * gv[ni] + ev[ni];
                    }
            if (st == 1) {
#pragma unroll
                for (int mt = 0; mt < 3; mt++)
                    if (mt < mtc)
#pragma unroll
                        for (int r = 0; r < 4; r++) {
                            int beta = (mtb + mt) * 16 + quad * 4 + r + 1;
                            bool ok = (unsigned)(l0 + beta - 9) < (unsigned)L_;
#pragma unroll
                            for (int ni = 0; ni < 6; ni++)
                                bout[beta * LDW + col0 + ni * 16] = (__bf16)(ok ? acc[mt][ni][r] : 0.f);
                        }
            } else {
                // ---- head: dot with lin_w, cross-wave reduce, store dur_preds ----
                float lwv[6];
#pragma unroll
                for (int ni = 0; ni < 6; ni++) lwv[ni] = lw[col0 + ni * 16];
#pragma unroll
                for (int mt = 0; mt < 3; mt++)
                    if (mt < mtc)
#pragma unroll
                        for (int r = 0; r < 4; r++) {
                            float p = 0.f;
#pragma unroll
                            for (int ni = 0; ni < 6; ni++) p += acc[mt][ni][r] * lwv[ni];
#pragma unroll
                            for (int d = 1; d < 16; d <<= 1) p += __shfl_xor(p, d);
                            if (lx == 0) {
                                int beta = (mtb + mt) * 16 + quad * 4 + r + 1;
                                red1[beta * 8 + wave] = p;
                            }
                        }
                __syncthreads();
                if (tid < 64) {
                    int beta = tid + 9;
                    int tile = (beta - 1) >> 4;
                    int base = (tile >= 3) ? 4 : 0;
                    float sacc = lb[0];
#pragma unroll
                    for (int k = 0; k < 4; k++) sacc += red1[beta * 8 + base + k];
                    out_dur[m0 + tid] = sacc;
                }
            }
        } else {
            // ---- plain write (conv1a / conv2a outputs) ----
#pragma unroll
            for (int mt = 0; mt < 3; mt++)
                if (mt < mtc)
#pragma unroll
                    for (int r = 0; r < 4; r++) {
                        int beta = (mtb + mt) * 16 + quad * 4 + r + 1;
                        bool ok = (unsigned)(l0 + beta - 9) < (unsigned)L_;
#pragma unroll
                        for (int ni = 0; ni < 6; ni++)
                            bout[beta * LDW + col0 + ni * 16] = (__bf16)(ok ? acc[mt][ni][r] : 0.f);
                    }
        }
        __syncthreads();
    }
}

extern "C" void kernel_launch(void* const* d_in, const int* in_sizes, int n_in,
                              void* d_out, int out_size, void* d_ws, size_t ws_size,
                              hipStream_t stream) {
    const float* x       = (const float*)d_in[0];
    const int*   dur     = (const int*)d_in[1];
    const float* c1a_w   = (const float*)d_in[2];
    const float* c1a_b   = (const float*)d_in[3];
    const float* c1b_w   = (const float*)d_in[4];
    const float* c1b_b   = (const float*)d_in[5];
    const float* ln1_g   = (const float*)d_in[6];
    const float* ln1_b   = (const float*)d_in[7];
    const float* c2a_w   = (const float*)d_in[8];
    const float* c2a_b   = (const float*)d_in[9];
    const float* c2b_w   = (const float*)d_in[10];
    const float* c2b_b   = (const float*)d_in[11];
    const float* ln2_g   = (const float*)d_in[12];
    const float* ln2_b   = (const float*)d_in[13];
    const float* lin_w   = (const float*)d_in[14];
    const float* lin_b   = (const float*)d_in[15];

    const int T = (out_size - B_ * L_) / (B_ * D_);
    float* out_gather = (float*)d_out;
    float* out_dur    = (float*)d_out + (size_t)B_ * T * D_;

    // workspace: 4 repacked weights
    char* p = (char*)d_ws;
    __bf16* w1a = (__bf16*)p; p += (size_t)D_ * KTOT * 2;
    __bf16* w1b = (__bf16*)p; p += (size_t)D_ * KTOT * 2;
    __bf16* w2a = (__bf16*)p; p += (size_t)D_ * KTOT * 2;
    __bf16* w2b = (__bf16*)p; p += (size_t)D_ * KTOT * 2;

    // K_A: repack + scatter(self-cum) + ztail, one launch
    mega_prep_lr<<<RPTOT + SCAT + ZT, 256, 0, stream>>>(
        c1a_w, c1b_w, c2a_w, c2b_w, w1a, w1b, w2a, w2b,
        dur, x, out_gather, T);

    // K_B: fused predictor (needs repacked weights)
    const size_t smem = (size_t)2 * BUFE * 2 + (BROWS * 8 * 2 + BROWS * 2) * 4;  // 134480 B
    static bool attr_set = false;
    if (!attr_set) {
        hipFuncSetAttribute((const void*)fused_predictor,
                            hipFuncAttributeMaxDynamicSharedMemorySize, (int)smem);
        attr_set = true;
    }
    fused_predictor<<<256, 512, smem, stream>>>(
        x, w1a, c1a_b, w1b, c1b_b, ln1_g, ln1_b,
        w2a, c2a_b, w2b, c2b_b, ln2_g, ln2_b,
        lin_w, lin_b, out_dur);
}

// Round 15
// 226.119 us; speedup vs baseline: 1.0041x; 1.0041x over previous
//
#include <hip/hip_runtime.h>

#define B_   32
#define L_   512
#define D_   384
#define M_   (B_*L_)    // 16384 rows
#define KTOT (D_*3)     // 1152 GEMM K
#define LDW  392        // LDS row stride in bf16 elems (784B: 16B-aligned, 2-way bank alias)
#define BROWS 82        // 80 data rows + 2 guard rows
#define BUFE (BROWS*LDW)
#define RPBLK 1728      // repack blocks per weight (1728*256 == D_*KTOT exactly)
#define RPTOT (4*RPBLK) // 6912
#define SCAT  8192      // scatter blocks (2 phonemes each)
#define ZT    (16*B_)   // 512 ztail blocks

typedef __bf16 bf16x8 __attribute__((ext_vector_type(8)));
typedef float  floatx4 __attribute__((ext_vector_type(4)));

// ================= K_A: repack + scatter(self-cum) + ztail, ONE launch ============
// r18-proven. Blocks [0, RPTOT): weight repack. Blocks [RPTOT, RPTOT+SCAT):
// scatter, 2 phonemes/block, self-computed cum (wave-0 scan into LDS).
// Blocks [RPTOT+SCAT, +ZT): tail zero-fill, 16 blocks/batch.
// ~180 MB of traffic -> ~28 us floor; measured ~30 us. Near its roofline.
// Session ledger: launch-count is the lever that worked here (5->3->2 launches
// = -20 us total, ~9 us/node); r19's fused||scatter co-residency REGRESSED
// (scatter traffic interferes with fused's L2 B-stream). Keep 2 launches.
__global__ __launch_bounds__(256) void mega_prep_lr(const float* __restrict__ wa,
                                                    const float* __restrict__ wb,
                                                    const float* __restrict__ wc,
                                                    const float* __restrict__ wd,
                                                    __bf16* __restrict__ oa,
                                                    __bf16* __restrict__ ob,
                                                    __bf16* __restrict__ oc,
                                                    __bf16* __restrict__ od,
                                                    const int* __restrict__ dur,
                                                    const float* __restrict__ x,
                                                    float* __restrict__ out, int T)
{
    __shared__ int scum[512];
    int bx = blockIdx.x;

    if (bx < RPTOT) {
        // ---- weight repack: W3[((c*24+t)*64+lane)*8+j] = w[o][kflat] ----
        int wi  = bx / RPBLK;
        int idx = (bx - wi * RPBLK) * 256 + threadIdx.x;
        const float* w; __bf16* o_;
        switch (wi) {
            case 0:  w = wa; o_ = oa; break;
            case 1:  w = wb; o_ = ob; break;
            case 2:  w = wc; o_ = oc; break;
            default: w = wd; o_ = od; break;
        }
        int j  = idx & 7;
        int l  = (idx >> 3) & 63;
        int ct = idx >> 9;          // c*24 + t
        int c  = ct / 24;
        int t  = ct - c * 24;
        int o  = t * 16 + (l & 15);
        int kflat = c * 32 + (l >> 4) * 8 + j;
        int s  = kflat / D_;
        int i  = kflat - s * D_;
        o_[idx] = (__bf16)w[(o * D_ + i) * 3 + s];
        return;
    }

    if (bx < RPTOT + SCAT) {
        // ---- scatter: block handles phonemes pl0, pl0+1 (same batch) ----
        int sx  = bx - RPTOT;
        int pl0 = sx * 2;
        int b   = pl0 >> 9;
        const int* db = dur + b * L_;
        if (threadIdx.x < 64) {
            int lane = threadIdx.x;
            int v[8], s = 0;
#pragma unroll
            for (int i = 0; i < 8; i++) { v[i] = db[lane * 8 + i]; s += v[i]; }
            int ex = s;
#pragma unroll
            for (int off = 1; off < 64; off <<= 1) {
                int n = __shfl_up(ex, off);
                if (lane >= off) ex += n;
            }
            ex -= s;
            int c = ex;
#pragma unroll
            for (int i = 0; i < 8; i++) { c += v[i]; scum[lane * 8 + i] = c; }
        }
        __syncthreads();
        int sub = threadIdx.x >> 7;               // 0 or 1
        int q   = threadIdx.x & 127;
        int l   = (pl0 & 511) + sub;
        int e = scum[l];
        int s = l ? scum[l - 1] : 0;
        if (e == s || q >= 96) return;
        int pl = b * L_ + l;
        float4 v = *(const float4*)(x + (size_t)pl * D_ + q * 4);
        float* ob_ = out + ((size_t)b * T) * D_ + q * 4;
        for (int t = s; t < e; ++t)
            *(float4*)(ob_ + (size_t)t * D_) = v;
        return;
    }

    // ---- tail zero-fill [total_b, T): 16 blocks per batch ----
    int zb = bx - RPTOT - SCAT;
    int bxi = zb & 15;
    int b   = zb >> 4;
    if (threadIdx.x < 64) {
        int lane = threadIdx.x;
        int s = 0;
#pragma unroll
        for (int i = 0; i < 8; i++) s += dur[b * L_ + lane * 8 + i];
#pragma unroll
        for (int off = 1; off < 64; off <<= 1) s += __shfl_xor(s, off);
        if (lane == 0) scum[0] = s;
    }
    __syncthreads();
    int total = scum[0];
    int nfr = T - total;
    if (nfr <= 0) return;
    float* base = out + ((size_t)b * T + total) * D_;
    int n4 = nfr * 96;                // float4 stores
    for (int i = bxi * 256 + threadIdx.x; i < n4; i += 4096) {
        int fr = i / 96, q = i - fr * 96;
        *(float4*)(base + (size_t)fr * D_ + q * 4) = make_float4(0.f, 0.f, 0.f, 0.f);
    }
}

// ================= K_B: fused DurationPredictor (r20 final, best measured) ========
// 512 threads (8 waves) own 64 output rows. 2M x 4N wave decomposition:
// ng = wave&3 owns cols [ng*96, ng*96+96) (6 n-tiles); mg = wave>>2 owns
// m-tiles {0,1,2} or {3,4}. Wave pair (w, w+4) shares ng on the same SIMD
// (L1 dedup of B). bg prefetched 2-ahead, af double-buffered 1-ahead (r20).
// PLATEAU NOTE (r9-r21 ledger): this structure is a latency-bound fixed point
// at the HW-forced 2 waves/SIMD (134 KB dynamic LDS -> 1 block/CU). Refuted
// alternatives: 16/12-wave blocks (VGPR caps force spills; 4 attempts),
// per-step LDS-B pipeline (-20%), in-place LDS + co-residency (-14 us),
// 32-row blocks (B traffic scales inversely with rows/block),
// amdgpu_waves_per_eu(2,2) (null: allocator lands at 116 regs regardless).
__global__ __launch_bounds__(512, 1) void fused_predictor(
    const float* __restrict__ x,
    const __bf16* __restrict__ w1a, const float* __restrict__ b1a,
    const __bf16* __restrict__ w1b, const float* __restrict__ b1b,
    const float* __restrict__ g1,  const float* __restrict__ e1,
    const __bf16* __restrict__ w2a, const float* __restrict__ b2a,
    const __bf16* __restrict__ w2b, const float* __restrict__ b2b,
    const float* __restrict__ g2,  const float* __restrict__ e2,
    const float* __restrict__ lw,  const float* __restrict__ lb,
    float* __restrict__ out_dur)
{
    extern __shared__ char smem_raw[];
    __bf16* bufA = (__bf16*)smem_raw;
    __bf16* bufB = bufA + BUFE;
    float*  red1 = (float*)(bufB + BUFE);    // [BROWS][8]
    float*  red2 = red1 + BROWS * 8;         // [BROWS][8]
    float*  minv = red2 + BROWS * 8;         // [BROWS][2]

    const int m0 = blockIdx.x * 64;
    const int l0 = m0 & 511;
    const int b0 = m0 - l0;

    const int tid  = threadIdx.x;
    const int wave = tid >> 6;        // 0..7
    const int lane = tid & 63;
    const int quad = lane >> 4;
    const int lx   = lane & 15;
    const int ng   = wave & 3;        // N-group: cols [ng*96, ng*96+96)
    const int mg   = wave >> 2;       // M-group: 0 -> m-tiles 0..2, 1 -> 3..4
    const int mtc  = mg ? 2 : 3;      // tiles this wave computes
    const int mtb  = mg ? 3 : 0;      // first tile index

    bf16x8 kz;
#pragma unroll
    for (int z = 0; z < 8; z++) kz[z] = (__bf16)0.f;

    // ---- stage x -> bufA (fp32->bf16, zero outside seq); zero bufB guards ----
    for (int c = tid; c < BROWS * 48; c += 512) {
        int beta = c / 48, q = c - beta * 48;
        int l = l0 + beta - 9;
        bf16x8 v = kz;
        if ((unsigned)l < (unsigned)L_) {
            const float* xr = x + (size_t)(b0 + l) * D_ + q * 8;
            const float4 f0 = *(const float4*)xr;
            const float4 f1 = *(const float4*)(xr + 4);
            v[0] = (__bf16)f0.x; v[1] = (__bf16)f0.y; v[2] = (__bf16)f0.z; v[3] = (__bf16)f0.w;
            v[4] = (__bf16)f1.x; v[5] = (__bf16)f1.y; v[6] = (__bf16)f1.z; v[7] = (__bf16)f1.w;
        }
        *(bf16x8*)(&bufA[beta * LDW + q * 8]) = v;
    }
    for (int c = tid; c < 2 * 48; c += 512) {
        int beta = (c < 48) ? 0 : 81, q = c % 48;
        *(bf16x8*)(&bufB[beta * LDW + q * 8]) = kz;
    }
    __syncthreads();

    const int t0   = ng * 6;                  // first n-tile of this wave
    const int col0 = ng * 96 + lx;            // col for ni: col0 + ni*16

    floatx4 acc[3][6];
    bf16x8  bg[3][6];

    for (int st = 0; st < 4; st++) {
        const __bf16* bin  = (st & 1) ? bufB : bufA;
        __bf16*       bout = (st & 1) ? bufA : bufB;
        const __bf16* Wp = (st == 0) ? w1a : (st == 1) ? w1b : (st == 2) ? w2a : w2b;
        const float*  bp = (st == 0) ? b1a : (st == 1) ? b1b : (st == 2) ? b2a : b2b;

#pragma unroll
        for (int mt = 0; mt < 3; mt++)
            if (mt < mtc)
#pragma unroll
                for (int ni = 0; ni < 6; ni++)
#pragma unroll
                    for (int r = 0; r < 4; r++) acc[mt][ni][r] = 0.f;

        const char* pb0 = (const char*)Wp + ((size_t)t0 * 64 + lane) * 16;
        auto loadB = [&](int buf, int n) {
            int it = n / 3, s = n - it * 3;
            const char* p = pb0 + (size_t)(s * 12 + it) * 24576;
#pragma unroll
            for (int ni = 0; ni < 6; ni++)
                bg[buf][ni] = *(const bf16x8*)(p + ni * 1024);
        };
        loadB(0, 0); loadB(1, 1);

        const __bf16* ab = bin + (mtb * 16 + lx) * LDW + quad * 8;
        bf16x8 af[2][3];
        auto loadA = [&](int bi, int n) {
            int it = n / 3, s = n - it * 3;
            af[bi][0] = *(const bf16x8*)(ab + (s) * LDW + it * 32);
            af[bi][1] = *(const bf16x8*)(ab + (16 + s) * LDW + it * 32);
            if (mtc == 3)
                af[bi][2] = *(const bf16x8*)(ab + (32 + s) * LDW + it * 32);
        };
        loadA(0, 0);
#pragma unroll
        for (int n = 0; n < 36; n++) {
            if (n + 2 < 36) loadB((n + 2) % 3, n + 2);
            if (n + 1 < 36) loadA((n + 1) & 1, n + 1);
            const int ai = n & 1;
            __builtin_amdgcn_s_setprio(1);
#pragma unroll
            for (int ni = 0; ni < 6; ni++) {
                acc[0][ni] = __builtin_amdgcn_mfma_f32_16x16x32_bf16(af[ai][0], bg[n % 3][ni], acc[0][ni], 0, 0, 0);
                acc[1][ni] = __builtin_amdgcn_mfma_f32_16x16x32_bf16(af[ai][1], bg[n % 3][ni], acc[1][ni], 0, 0, 0);
            }
            if (mtc == 3) {
#pragma unroll
                for (int ni = 0; ni < 6; ni++)
                    acc[2][ni] = __builtin_amdgcn_mfma_f32_16x16x32_bf16(af[ai][2], bg[n % 3][ni], acc[2][ni], 0, 0, 0);
            }
            __builtin_amdgcn_s_setprio(0);
        }

        // ---- epilogue: bias + relu (in regs) ----
        float bv[6];
#pragma unroll
        for (int ni = 0; ni < 6; ni++) bv[ni] = bp[col0 + ni * 16];
#pragma unroll
        for (int mt = 0; mt < 3; mt++)
            if (mt < mtc)
#pragma unroll
                for (int ni = 0; ni < 6; ni++)
#pragma unroll
                    for (int r = 0; r < 4; r++) {
                        float vv = acc[mt][ni][r] + bv[ni];
                        acc[mt][ni][r] = vv > 0.f ? vv : 0.f;
                    }

        if (st == 1 || st == 3) {
            // ---- LayerNorm: row stats via lx-shuffle + cross-wave LDS reduce ----
#pragma unroll
            for (int mt = 0; mt < 3; mt++)
                if (mt < mtc)
#pragma unroll
                    for (int r = 0; r < 4; r++) {
                        float s1 = 0.f, s2 = 0.f;
#pragma unroll
                        for (int ni = 0; ni < 6; ni++) {
                            s1 += acc[mt][ni][r];
                            s2 += acc[mt][ni][r] * acc[mt][ni][r];
                        }
#pragma unroll
                        for (int d = 1; d < 16; d <<= 1) {
                            s1 += __shfl_xor(s1, d);
                            s2 += __shfl_xor(s2, d);
                        }
                        if (lx == 0) {
                            int beta = (mtb + mt) * 16 + quad * 4 + r + 1;
                            red1[beta * 8 + wave] = s1;
                            red2[beta * 8 + wave] = s2;
                        }
                    }
            __syncthreads();
            if (tid < BROWS) {
                // owner waves of row tid: tiles 0..2 -> w in {0..3}; tiles 3..4 -> {4..7}
                int tile = (tid - 1) >> 4;
                int base = (tile >= 3) ? 4 : 0;
                float s1 = 0.f, s2 = 0.f;
#pragma unroll
                for (int k = 0; k < 4; k++) { s1 += red1[tid * 8 + base + k]; s2 += red2[tid * 8 + base + k]; }
                float mean = s1 * (1.f / D_);
                float var  = s2 * (1.f / D_) - mean * mean;
                minv[tid * 2]     = mean;
                minv[tid * 2 + 1] = rsqrtf(var + 1e-5f);
            }
            __syncthreads();
            const float* gp = (st == 1) ? g1 : g2;
            const float* ep = (st == 1) ? e1 : e2;
            float gv[6], ev[6];
#pragma unroll
            for (int ni = 0; ni < 6; ni++) { gv[ni] = gp[col0 + ni * 16]; ev[ni] = ep[col0 + ni * 16]; }
#pragma unroll
            for (int mt = 0; mt < 3; mt++)
                if (mt < mtc)
#pragma unroll
                    for (int r = 0; r < 4; r++) {
                        int beta = (mtb + mt) * 16 + quad * 4 + r + 1;
                        float mean = minv[beta * 2], inv = minv[beta * 2 + 1];
#pragma unroll
                        for (int ni = 0; ni < 6; ni++)
                            acc[mt][ni][r] = (acc[mt][ni][r] - mean) * inv * gv[ni] + ev[ni];
                    }
            if (st == 1) {
#pragma unroll
                for (int mt = 0; mt < 3; mt++)
                    if (mt < mtc)
#pragma unroll
                        for (int r = 0; r < 4; r++) {
                            int beta = (mtb + mt) * 16 + quad * 4 + r + 1;
                            bool ok = (unsigned)(l0 + beta - 9) < (unsigned)L_;
#pragma unroll
                            for (int ni = 0; ni < 6; ni++)
                                bout[beta * LDW + col0 + ni * 16] = (__bf16)(ok ? acc[mt][ni][r] : 0.f);
                        }
            } else {
                // ---- head: dot with lin_w, cross-wave reduce, store dur_preds ----
                float lwv[6];
#pragma unroll
                for (int ni = 0; ni < 6; ni++) lwv[ni] = lw[col0 + ni * 16];
#pragma unroll
                for (int mt = 0; mt < 3; mt++)
                    if (mt < mtc)
#pragma unroll
                        for (int r = 0; r < 4; r++) {
                            float p = 0.f;
#pragma unroll
                            for (int ni = 0; ni < 6; ni++) p += acc[mt][ni][r] * lwv[ni];
#pragma unroll
                            for (int d = 1; d < 16; d <<= 1) p += __shfl_xor(p, d);
                            if (lx == 0) {
                                int beta = (mtb + mt) * 16 + quad * 4 + r + 1;
                                red1[beta * 8 + wave] = p;
                            }
                        }
                __syncthreads();
                if (tid < 64) {
                    int beta = tid + 9;
                    int tile = (beta - 1) >> 4;
                    int base = (tile >= 3) ? 4 : 0;
                    float sacc = lb[0];
#pragma unroll
                    for (int k = 0; k < 4; k++) sacc += red1[beta * 8 + base + k];
                    out_dur[m0 + tid] = sacc;
                }
            }
        } else {
            // ---- plain write (conv1a / conv2a outputs) ----
#pragma unroll
            for (int mt = 0; mt < 3; mt++)
                if (mt < mtc)
#pragma unroll
                    for (int r = 0; r < 4; r++) {
                        int beta = (mtb + mt) * 16 + quad * 4 + r + 1;
                        bool ok = (unsigned)(l0 + beta - 9) < (unsigned)L_;
#pragma unroll
                        for (int ni = 0; ni < 6; ni++)
                            bout[beta * LDW + col0 + ni * 16] = (__bf16)(ok ? acc[mt][ni][r] : 0.f);
                    }
        }
        __syncthreads();
    }
}

extern "C" void kernel_launch(void* const* d_in, const int* in_sizes, int n_in,
                              void* d_out, int out_size, void* d_ws, size_t ws_size,
                              hipStream_t stream) {
    const float* x       = (const float*)d_in[0];
    const int*   dur     = (const int*)d_in[1];
    const float* c1a_w   = (const float*)d_in[2];
    const float* c1a_b   = (const float*)d_in[3];
    const float* c1b_w   = (const float*)d_in[4];
    const float* c1b_b   = (const float*)d_in[5];
    const float* ln1_g   = (const float*)d_in[6];
    const float* ln1_b   = (const float*)d_in[7];
    const float* c2a_w   = (const float*)d_in[8];
    const float* c2a_b   = (const float*)d_in[9];
    const float* c2b_w   = (const float*)d_in[10];
    const float* c2b_b   = (const float*)d_in[11];
    const float* ln2_g   = (const float*)d_in[12];
    const float* ln2_b   = (const float*)d_in[13];
    const float* lin_w   = (const float*)d_in[14];
    const float* lin_b   = (const float*)d_in[15];

    const int T = (out_size - B_ * L_) / (B_ * D_);
    float* out_gather = (float*)d_out;
    float* out_dur    = (float*)d_out + (size_t)B_ * T * D_;

    // workspace: 4 repacked weights
    char* p = (char*)d_ws;
    __bf16* w1a = (__bf16*)p; p += (size_t)D_ * KTOT * 2;
    __bf16* w1b = (__bf16*)p; p += (size_t)D_ * KTOT * 2;
    __bf16* w2a = (__bf16*)p; p += (size_t)D_ * KTOT * 2;
    __bf16* w2b = (__bf16*)p; p += (size_t)D_ * KTOT * 2;

    // K_A: repack + scatter(self-cum) + ztail, one launch
    mega_prep_lr<<<RPTOT + SCAT + ZT, 256, 0, stream>>>(
        c1a_w, c1b_w, c2a_w, c2b_w, w1a, w1b, w2a, w2b,
        dur, x, out_gather, T);

    // K_B: fused predictor (needs repacked weights)
    const size_t smem = (size_t)2 * BUFE * 2 + (BROWS * 8 * 2 + BROWS * 2) * 4;  // 134480 B
    static bool attr_set = false;
    if (!attr_set) {
        hipFuncSetAttribute((const void*)fused_predictor,
                            hipFuncAttributeMaxDynamicSharedMemorySize, (int)smem);
        attr_set = true;
    }
    fused_predictor<<<256, 512, smem, stream>>>(
        x, w1a, c1a_b, w1b, c1b_b, ln1_g, ln1_b,
        w2a, c2a_b, w2b, c2b_b, ln2_g, ln2_b,
        lin_w, lin_b, out_dur);
}